// Round 2
// baseline (245.954 us; speedup 1.0000x reference)
//
#include <hip/hip_runtime.h>
#include <math.h>

#define GAMMA 0.3f
#define EPS 1e-6f
#define B_SZ 16
#define NH 32
#define KF 32768
#define KI 16384
#define KHEADS 7   // ceil(0.2 * 32)

// ---- workspace layout (float indices) ----
constexpr int OFF_MU   = 0;                    // 64  (b*4+f)
constexpr int OFF_SD   = 64;                   // 64
constexpr int OFF_SPOS = 128;                  // 512
constexpr int OFF_SNEG = 640;                  // 512
constexpr int OFF_CP   = 1152;                 // 512  gamma*m_pos
constexpr int OFF_CN   = 1664;                 // 512  gamma*m_neg
constexpr int OFF_RF   = 4096;                 // B*KI
constexpr int OFF_LRF  = OFF_RF  + B_SZ * KI;  // B*KI
constexpr int OFF_RFF  = OFF_LRF + B_SZ * KI;  // B*KF  rf expanded to full K, 0 off-mask
constexpr int OFF_LRFF = OFF_RFF + B_SZ * KF;  // B*KF
// total ≈ 1,576,960 floats ≈ 6.0 MiB

// ---- per-(b,feat) mean / (std+eps), double accumulation ----
__global__ __launch_bounds__(256) void k_stats(const float* __restrict__ fC,
        const float* __restrict__ fA, const float* __restrict__ fD,
        const float* __restrict__ fB, float* __restrict__ ws) {
    int bid = blockIdx.x;            // b*4 + f
    int b = bid >> 2, f = bid & 3;
    const float* src;
    if (f == 0) src = fC; else if (f == 1) src = fA; else if (f == 2) src = fD; else src = fB;
    src += (size_t)b * KI;
    int t = threadIdx.x;
    __shared__ double red[256];
    double s = 0.0;
    for (int i = t; i < KI; i += 256) s += (double)src[i];
    red[t] = s; __syncthreads();
    for (int off = 128; off > 0; off >>= 1) { if (t < off) red[t] += red[t + off]; __syncthreads(); }
    double mu = red[0] * (1.0 / KI);
    __syncthreads();
    double s2 = 0.0;
    for (int i = t; i < KI; i += 256) { double d = (double)src[i] - mu; s2 += d * d; }
    red[t] = s2; __syncthreads();
    for (int off = 128; off > 0; off >>= 1) { if (t < off) red[t] += red[t + off]; __syncthreads(); }
    if (t == 0) {
        double var = red[0] * (1.0 / KI);
        ws[OFF_MU + bid] = (float)mu;
        ws[OFF_SD + bid] = (float)(sqrt(var) + (double)EPS);
    }
}

// ---- elementwise rf / low_rf ----
__global__ __launch_bounds__(256) void k_rf(const float* __restrict__ fC,
        const float* __restrict__ fA, const float* __restrict__ fD,
        const float* __restrict__ fB, float* __restrict__ ws) {
    int e = blockIdx.x * 256 + threadIdx.x;   // grid 1024 -> exactly B*KI
    int b = e >> 14;
    const float* mu = ws + OFF_MU + b * 4;
    const float* sd = ws + OFF_SD + b * 4;
    float zC = (fC[e] - mu[0]) / sd[0];
    float Ct = fmaxf(zC, 0.f);
    float zA = (fA[e] - mu[1]) / sd[1];
    float At = 1.f / (1.f + expf(-zA));
    float zD = (fD[e] - mu[2]) / sd[2];
    float Dt = 1.f / (1.f + expf(-zD));
    float zB = (fB[e] - mu[3]) / sd[3];
    float Bt = 1.f / (1.f + expf(-zB));
    float denom = fmaxf(1.f + 0.5f * (Dt + Bt), EPS);
    float rf = fmaxf(Ct * At / denom, 0.f);
    ws[OFF_RF + e]  = rf;
    ws[OFF_LRF + e] = fmaxf(1.f - rf, 0.f);
}

// ---- per-row mask scan -> rf_full / lrf_full (0 where mask==0) ----
__global__ __launch_bounds__(1024) void k_expand(const int* __restrict__ mask,
                                                 float* __restrict__ ws) {
    int b = blockIdx.x, t = threadIdx.x;
    const int* mrow = mask + (size_t)b * KF;
    int base = t * 32;
    int mv[32];
    int cnt = 0;
    #pragma unroll
    for (int i = 0; i < 32; ++i) { mv[i] = mrow[base + i]; cnt += (mv[i] != 0); }
    __shared__ int sc[1024];
    sc[t] = cnt; __syncthreads();
    for (int off = 1; off < 1024; off <<= 1) {
        int v = (t >= off) ? sc[t - off] : 0;
        __syncthreads();
        sc[t] += v;
        __syncthreads();
    }
    int r = sc[t] - cnt;   // exclusive prefix = rank of first element in my chunk
    const float* rf   = ws + OFF_RF  + b * KI;
    const float* lrf  = ws + OFF_LRF + b * KI;
    float* rff  = ws + OFF_RFF  + (size_t)b * KF + base;
    float* lrff = ws + OFF_LRFF + (size_t)b * KF + base;
    #pragma unroll
    for (int i = 0; i < 32; ++i) {
        float v = 0.f, l = 0.f;
        if (mv[i]) { v = rf[r]; l = lrf[r]; ++r; }
        rff[i] = v; lrff[i] = l;
    }
}

// ---- per-(b,h) online masked softmax -> s_pos, s_neg ----
__global__ __launch_bounds__(256) void k_scores(const float* __restrict__ attn,
        const int* __restrict__ mask, float* __restrict__ ws) {
    int bh = blockIdx.x;
    int b = bh >> 5;
    const float* xr = attn + (size_t)bh * KF;
    const int* mr = mask + (size_t)b * KF;
    const float* rff  = ws + OFF_RFF  + (size_t)b * KF;
    const float* lrff = ws + OFF_LRFF + (size_t)b * KF;
    int t = threadIdx.x;
    float mx = -INFINITY, S = 0.f, P = 0.f, N = 0.f;
    #pragma unroll 4
    for (int it = 0; it < KF / (256 * 4); ++it) {
        int k = (t + it * 256) * 4;
        float4 xs = *(const float4*)(xr + k);
        int4   mm = *(const int4*)(mr + k);
        float4 rv = *(const float4*)(rff + k);
        float4 lv = *(const float4*)(lrff + k);
        float xa[4] = {xs.x, xs.y, xs.z, xs.w};
        int   ma[4] = {mm.x, mm.y, mm.z, mm.w};
        float ra[4] = {rv.x, rv.y, rv.z, rv.w};
        float la[4] = {lv.x, lv.y, lv.z, lv.w};
        #pragma unroll
        for (int j = 0; j < 4; ++j) {
            if (ma[j]) {
                float x = xa[j];
                if (x > mx) {
                    float scale = __expf(mx - x);   // exp(-inf)=0 handles first element
                    S = S * scale + 1.f;
                    P = P * scale + ra[j];
                    N = N * scale + la[j];
                    mx = x;
                } else {
                    float e = __expf(x - mx);
                    S += e; P += e * ra[j]; N += e * la[j];
                }
            }
        }
    }
    __shared__ float rm[256], rs[256], rp[256], rn[256];
    rm[t] = mx; rs[t] = S; rp[t] = P; rn[t] = N;
    __syncthreads();
    for (int off = 128; off > 0; off >>= 1) {
        if (t < off) {
            float m1 = rm[t], m2 = rm[t + off];
            float M = fmaxf(m1, m2);
            float a = (m1 == -INFINITY) ? 0.f : __expf(m1 - M);
            float c = (m2 == -INFINITY) ? 0.f : __expf(m2 - M);
            rs[t] = rs[t] * a + rs[t + off] * c;
            rp[t] = rp[t] * a + rp[t + off] * c;
            rn[t] = rn[t] * a + rn[t + off] * c;
            rm[t] = M;
        }
        __syncthreads();
    }
    if (t == 0) {
        float S0 = rs[0];
        ws[OFF_SPOS + bh] = rp[0] / S0;
        ws[OFF_SNEG + bh] = rn[0] / S0;
    }
}

// ---- top-7 head selection (jax top_k semantics: value desc, tie -> lower index,
//      only strictly-positive values count) ----
__global__ __launch_bounds__(64) void k_topk(float* __restrict__ ws) {
    int b = blockIdx.x, t = threadIdx.x;
    __shared__ float v[NH];
    float sp = 0.f;
    if (t < NH) { sp = ws[OFF_SPOS + b * NH + t]; v[t] = sp; }
    __syncthreads();
    bool mpos = false;
    if (t < NH) {
        int cnt = 0;
        for (int h = 0; h < NH; ++h) { float o = v[h]; cnt += (o > sp) || (o == sp && h < t); }
        mpos = (cnt < KHEADS) && (sp > 0.f);
        ws[OFF_CP + b * NH + t] = mpos ? GAMMA : 0.f;
    }
    __syncthreads();
    float nv = -INFINITY;
    if (t < NH) { nv = mpos ? -INFINITY : ws[OFF_SNEG + b * NH + t]; v[t] = nv; }
    __syncthreads();
    if (t < NH) {
        int cnt = 0;
        for (int h = 0; h < NH; ++h) { float o = v[h]; cnt += (o > nv) || (o == nv && h < t); }
        bool mneg = (cnt < KHEADS) && (nv > 0.f) && !mpos;
        ws[OFF_CN + b * NH + t] = mneg ? GAMMA : 0.f;
    }
}

// ---- streaming epilogue: out = attn + cp*rf_full - cn*lrf_full ----
__global__ __launch_bounds__(256) void k_out(const float* __restrict__ attn,
        const float* __restrict__ ws, float* __restrict__ out) {
    const float* cp = ws + OFF_CP;
    const float* cn = ws + OFF_CN;
    const unsigned int nvec = (unsigned int)(B_SZ * NH) * (KF / 4);   // 4,194,304
    unsigned int stride = gridDim.x * blockDim.x;
    for (unsigned int u = blockIdx.x * blockDim.x + threadIdx.x; u < nvec; u += stride) {
        unsigned int flat = u * 4;
        unsigned int bh = flat >> 15;        // / KF
        unsigned int b  = bh >> 5;           // / NH
        unsigned int k  = flat & (KF - 1);
        float gp = cp[bh], gn = cn[bh];
        const float* rff  = ws + OFF_RFF  + ((size_t)b << 15);
        const float* lrff = ws + OFF_LRFF + ((size_t)b << 15);
        float4 xs = *(const float4*)(attn + flat);
        float4 rv = *(const float4*)(rff + k);
        float4 lv = *(const float4*)(lrff + k);
        float4 o;
        o.x = xs.x + gp * rv.x - gn * lv.x;
        o.y = xs.y + gp * rv.y - gn * lv.y;
        o.z = xs.z + gp * rv.z - gn * lv.z;
        o.w = xs.w + gp * rv.w - gn * lv.w;
        *(float4*)(out + flat) = o;
    }
}

extern "C" void kernel_launch(void* const* d_in, const int* in_sizes, int n_in,
                              void* d_out, int out_size, void* d_ws, size_t ws_size,
                              hipStream_t stream) {
    const float* attn = (const float*)d_in[0];   // f32 [B,H,KF]
    const int*   mask = (const int*)d_in[1];     // int32 [B,KF]
    const float* fC   = (const float*)d_in[2];   // f32 [B,KI]
    const float* fA   = (const float*)d_in[3];
    const float* fD   = (const float*)d_in[4];
    const float* fB   = (const float*)d_in[5];
    float* out = (float*)d_out;                  // f32 [B,H,KF]
    float* ws = (float*)d_ws;

    k_stats <<<B_SZ * 4, 256, 0, stream>>>(fC, fA, fD, fB, ws);
    k_rf    <<<(B_SZ * KI) / 256, 256, 0, stream>>>(fC, fA, fD, fB, ws);
    k_expand<<<B_SZ, 1024, 0, stream>>>(mask, ws);
    k_scores<<<B_SZ * NH, 256, 0, stream>>>(attn, mask, ws);
    k_topk  <<<B_SZ, 64, 0, stream>>>(ws);
    k_out   <<<4096, 256, 0, stream>>>(attn, ws, out);
}

// Round 3
// 161.280 us; speedup vs baseline: 1.5250x; 1.5250x over previous
//
#include <hip/hip_runtime.h>
#include <math.h>

#define GAMMA 0.3f
#define EPS 1e-6f
#define B_SZ 16
#define NH 32
#define KF 32768
#define KI 16384
#define KHEADS 7   // ceil(0.2 * 32)

// ---- workspace layout (float indices) ----
constexpr int OFF_MU   = 0;                    // 64  (b*4+f)
constexpr int OFF_SD   = 64;                   // 64
constexpr int OFF_SPOS = 128;                  // 512
constexpr int OFF_SNEG = 640;                  // 512
constexpr int OFF_CP   = 1152;                 // 512  gamma*m_pos
constexpr int OFF_CN   = 1664;                 // 512  gamma*m_neg
constexpr int IOFF_BSUM = 2176;                // 256 ints (per-2048-chunk mask counts)
constexpr int OFF_RF   = 4096;                 // B*KI
constexpr int OFF_LRF  = OFF_RF  + B_SZ * KI;  // B*KI
constexpr int OFF_RFF  = OFF_LRF + B_SZ * KI;  // B*KF  rf expanded to full K, 0 off-mask
constexpr int OFF_LRFF = OFF_RFF + B_SZ * KF;  // B*KF
// total ≈ 6.0 MiB

// ---- per-(b,feat) mean / (std+eps); single-pass double sum/sumsq, float4 loads ----
__global__ __launch_bounds__(256) void k_stats(const float* __restrict__ fC,
        const float* __restrict__ fA, const float* __restrict__ fD,
        const float* __restrict__ fB, float* __restrict__ ws) {
    int bid = blockIdx.x;            // b*4 + f
    int b = bid >> 2, f = bid & 3;
    const float* src;
    if (f == 0) src = fC; else if (f == 1) src = fA; else if (f == 2) src = fD; else src = fB;
    src += (size_t)b * KI;
    int t = threadIdx.x;
    double s = 0.0, s2 = 0.0;
    for (int i = t; i < KI / 4; i += 256) {
        float4 v = ((const float4*)src)[i];
        s  += (double)v.x + (double)v.y + (double)v.z + (double)v.w;
        s2 += (double)v.x * v.x + (double)v.y * v.y + (double)v.z * v.z + (double)v.w * v.w;
    }
    __shared__ double r1[256], r2[256];
    r1[t] = s; r2[t] = s2; __syncthreads();
    for (int off = 128; off > 0; off >>= 1) {
        if (t < off) { r1[t] += r1[t + off]; r2[t] += r2[t + off]; }
        __syncthreads();
    }
    if (t == 0) {
        double mu  = r1[0] * (1.0 / KI);
        double var = fmax(r2[0] * (1.0 / KI) - mu * mu, 0.0);
        ws[OFF_MU + bid] = (float)mu;
        ws[OFF_SD + bid] = (float)(sqrt(var) + (double)EPS);
    }
}

// ---- blocks [0,256): elementwise rf/low_rf (float4); blocks [256,512): mask chunk counts ----
__global__ __launch_bounds__(256) void k_rf_cnt(const float* __restrict__ fC,
        const float* __restrict__ fA, const float* __restrict__ fD,
        const float* __restrict__ fB, const int* __restrict__ mask,
        float* __restrict__ ws) {
    __shared__ int sred[256];
    int blk = blockIdx.x, t = threadIdx.x;
    if (blk < 256) {
        int base = blk * 1024 + t * 4;          // within one b-row (1024 | 16384)
        int b = base >> 14;
        const float* mu = ws + OFF_MU + b * 4;
        const float* sd = ws + OFF_SD + b * 4;
        float4 vC = *(const float4*)(fC + base);
        float4 vA = *(const float4*)(fA + base);
        float4 vD = *(const float4*)(fD + base);
        float4 vB = *(const float4*)(fB + base);
        float rf4[4], lrf4[4];
        float c4[4] = {vC.x, vC.y, vC.z, vC.w};
        float a4[4] = {vA.x, vA.y, vA.z, vA.w};
        float d4[4] = {vD.x, vD.y, vD.z, vD.w};
        float b4[4] = {vB.x, vB.y, vB.z, vB.w};
        #pragma unroll
        for (int j = 0; j < 4; ++j) {
            float Ct = fmaxf((c4[j] - mu[0]) / sd[0], 0.f);
            float At = 1.f / (1.f + __expf(-((a4[j] - mu[1]) / sd[1])));
            float Dt = 1.f / (1.f + __expf(-((d4[j] - mu[2]) / sd[2])));
            float Bt = 1.f / (1.f + __expf(-((b4[j] - mu[3]) / sd[3])));
            float denom = fmaxf(1.f + 0.5f * (Dt + Bt), EPS);
            float rf = fmaxf(Ct * At / denom, 0.f);
            rf4[j] = rf;
            lrf4[j] = fmaxf(1.f - rf, 0.f);
        }
        *(float4*)(ws + OFF_RF  + base) = *(float4*)rf4;
        *(float4*)(ws + OFF_LRF + base) = *(float4*)lrf4;
    } else {
        int cblk = blk - 256;                    // 0..255, 2048 ints each
        const int* mrow = mask + (size_t)cblk * 2048;
        int4 m0 = *(const int4*)(mrow + t * 8);
        int4 m1 = *(const int4*)(mrow + t * 8 + 4);
        int cnt = (m0.x != 0) + (m0.y != 0) + (m0.z != 0) + (m0.w != 0)
                + (m1.x != 0) + (m1.y != 0) + (m1.z != 0) + (m1.w != 0);
        sred[t] = cnt; __syncthreads();
        for (int off = 128; off > 0; off >>= 1) {
            if (t < off) sred[t] += sred[t + off];
            __syncthreads();
        }
        if (t == 0) ((int*)ws)[IOFF_BSUM + cblk] = sred[0];
    }
}

// ---- expand rf/lrf to full-K via decoupled scan (256 blocks, one 2048-chunk each) ----
__global__ __launch_bounds__(256) void k_expand(const int* __restrict__ mask,
                                                float* __restrict__ ws) {
    int blk = blockIdx.x, t = threadIdx.x;       // blk = b*16 + c
    int b = blk >> 4, c = blk & 15;
    const int* bsum = (const int*)ws + IOFF_BSUM;
    int boff = 0;
    for (int i = 0; i < c; ++i) boff += bsum[(b << 4) + i];   // ≤15 cached reads
    const int* mrow = mask + (size_t)blk * 2048;
    int4 m0 = *(const int4*)(mrow + t * 8);
    int4 m1 = *(const int4*)(mrow + t * 8 + 4);
    int mv[8] = {m0.x, m0.y, m0.z, m0.w, m1.x, m1.y, m1.z, m1.w};
    int cnt = 0;
    #pragma unroll
    for (int j = 0; j < 8; ++j) cnt += (mv[j] != 0);
    __shared__ int sc[256];
    sc[t] = cnt; __syncthreads();
    for (int off = 1; off < 256; off <<= 1) {
        int v = (t >= off) ? sc[t - off] : 0;
        __syncthreads();
        sc[t] += v;
        __syncthreads();
    }
    int r = boff + sc[t] - cnt;                  // rank of my first element
    const float* rf  = ws + OFF_RF  + b * KI;
    const float* lrf = ws + OFF_LRF + b * KI;
    float vr[8], vl[8];
    #pragma unroll
    for (int j = 0; j < 8; ++j) {
        if (mv[j]) { vr[j] = rf[r]; vl[j] = lrf[r]; ++r; }
        else       { vr[j] = 0.f;   vl[j] = 0.f; }
    }
    float* rff  = ws + OFF_RFF  + (size_t)blk * 2048 + t * 8;
    float* lrff = ws + OFF_LRFF + (size_t)blk * 2048 + t * 8;
    *(float4*)(rff)      = *(float4*)(vr);
    *(float4*)(rff + 4)  = *(float4*)(vr + 4);
    *(float4*)(lrff)     = *(float4*)(vl);
    *(float4*)(lrff + 4) = *(float4*)(vl + 4);
}

// ---- per-(b,h) masked-softmax scores, branchless (no max-subtraction: |x|<~6) ----
// on-mask rf+lrf >= 1, off-mask both 0  ->  indicator = (rv+lv > 0)
__global__ __launch_bounds__(256) void k_scores(const float* __restrict__ attn,
                                                float* __restrict__ ws) {
    int bh = blockIdx.x;
    int b = bh >> 5;
    const float* xr   = attn + (size_t)bh * KF;
    const float* rff  = ws + OFF_RFF  + (size_t)b * KF;
    const float* lrff = ws + OFF_LRFF + (size_t)b * KF;
    int t = threadIdx.x;
    float S = 0.f, P = 0.f, N = 0.f;
    #pragma unroll 4
    for (int it = 0; it < KF / (256 * 4); ++it) {
        int k = (it * 256 + t) * 4;
        float4 xs = *(const float4*)(xr + k);
        float4 rv = *(const float4*)(rff + k);
        float4 lv = *(const float4*)(lrff + k);
        float xa[4] = {xs.x, xs.y, xs.z, xs.w};
        float ra[4] = {rv.x, rv.y, rv.z, rv.w};
        float la[4] = {lv.x, lv.y, lv.z, lv.w};
        #pragma unroll
        for (int j = 0; j < 4; ++j) {
            float e = __expf(xa[j]);
            S += (ra[j] + la[j] > 0.f) ? e : 0.f;
            P = fmaf(e, ra[j], P);
            N = fmaf(e, la[j], N);
        }
    }
    __shared__ float rs[256], rp[256], rn[256];
    rs[t] = S; rp[t] = P; rn[t] = N;
    __syncthreads();
    for (int off = 128; off > 0; off >>= 1) {
        if (t < off) { rs[t] += rs[t + off]; rp[t] += rp[t + off]; rn[t] += rn[t + off]; }
        __syncthreads();
    }
    if (t == 0) {
        float S0 = rs[0];
        ws[OFF_SPOS + bh] = rp[0] / S0;
        ws[OFF_SNEG + bh] = rn[0] / S0;
    }
}

// ---- top-7 head selection (jax top_k: value desc, tie -> lower index, val>0 only) ----
__global__ __launch_bounds__(64) void k_topk(float* __restrict__ ws) {
    int b = blockIdx.x, t = threadIdx.x;
    __shared__ float v[NH];
    float sp = 0.f;
    if (t < NH) { sp = ws[OFF_SPOS + b * NH + t]; v[t] = sp; }
    __syncthreads();
    bool mpos = false;
    if (t < NH) {
        int cnt = 0;
        for (int h = 0; h < NH; ++h) { float o = v[h]; cnt += (o > sp) || (o == sp && h < t); }
        mpos = (cnt < KHEADS) && (sp > 0.f);
        ws[OFF_CP + b * NH + t] = mpos ? GAMMA : 0.f;
    }
    __syncthreads();
    float nv = -INFINITY;
    if (t < NH) { nv = mpos ? -INFINITY : ws[OFF_SNEG + b * NH + t]; v[t] = nv; }
    __syncthreads();
    if (t < NH) {
        int cnt = 0;
        for (int h = 0; h < NH; ++h) { float o = v[h]; cnt += (o > nv) || (o == nv && h < t); }
        bool mneg = (cnt < KHEADS) && (nv > 0.f) && !mpos;
        ws[OFF_CN + b * NH + t] = mneg ? GAMMA : 0.f;
    }
}

// ---- streaming epilogue: out = attn + cp*rf_full - cn*lrf_full (one float4/thread) ----
__global__ __launch_bounds__(256) void k_out(const float* __restrict__ attn,
        const float* __restrict__ ws, float* __restrict__ out) {
    unsigned int u = blockIdx.x * 256 + threadIdx.x;   // grid covers exactly B*H*KF/4
    unsigned int flat = u * 4;
    unsigned int bh = flat >> 15;        // / KF
    unsigned int b  = bh >> 5;           // / NH
    unsigned int k  = flat & (KF - 1);
    float gp = ws[OFF_CP + bh], gn = ws[OFF_CN + bh];
    const float* rff  = ws + OFF_RFF  + ((size_t)b << 15);
    const float* lrff = ws + OFF_LRFF + ((size_t)b << 15);
    float4 xs = *(const float4*)(attn + flat);
    float4 rv = *(const float4*)(rff + k);
    float4 lv = *(const float4*)(lrff + k);
    float4 o;
    o.x = xs.x + gp * rv.x - gn * lv.x;
    o.y = xs.y + gp * rv.y - gn * lv.y;
    o.z = xs.z + gp * rv.z - gn * lv.z;
    o.w = xs.w + gp * rv.w - gn * lv.w;
    *(float4*)(out + flat) = o;
}

extern "C" void kernel_launch(void* const* d_in, const int* in_sizes, int n_in,
                              void* d_out, int out_size, void* d_ws, size_t ws_size,
                              hipStream_t stream) {
    const float* attn = (const float*)d_in[0];   // f32 [B,H,KF]
    const int*   mask = (const int*)d_in[1];     // int32 [B,KF]
    const float* fC   = (const float*)d_in[2];   // f32 [B,KI]
    const float* fA   = (const float*)d_in[3];
    const float* fD   = (const float*)d_in[4];
    const float* fB   = (const float*)d_in[5];
    float* out = (float*)d_out;                  // f32 [B,H,KF]
    float* ws = (float*)d_ws;

    k_stats <<<B_SZ * 4, 256, 0, stream>>>(fC, fA, fD, fB, ws);
    k_rf_cnt<<<512, 256, 0, stream>>>(fC, fA, fD, fB, mask, ws);
    k_expand<<<256, 256, 0, stream>>>(mask, ws);
    k_scores<<<B_SZ * NH, 256, 0, stream>>>(attn, ws);
    k_topk  <<<B_SZ, 64, 0, stream>>>(ws);
    k_out   <<<(B_SZ * NH * KF / 4) / 256, 256, 0, stream>>>(attn, ws, out);
}

// Round 5
// 153.967 us; speedup vs baseline: 1.5974x; 1.0475x over previous
//
#include <hip/hip_runtime.h>
#include <math.h>

#define GAMMA 0.3f
#define EPS 1e-6f
#define B_SZ 16
#define NH 32
#define KF 32768
#define KI 16384
#define KHEADS 7   // ceil(0.2 * 32)

// ---- workspace layout (float indices) ----
constexpr int OFF_MU    = 0;                    // 64  (b*4+f)
constexpr int OFF_SD    = 64;                   // 64
constexpr int OFF_RAWS  = 128;                  // 512  raw softmax denom per (b,h)
constexpr int OFF_RAWP  = 640;                  // 512  raw pos numerator
constexpr int OFF_RAWN  = 1152;                 // 512  raw neg numerator
constexpr int IOFF_BSUM = 1664;                 // 256 ints (per-2048-chunk mask counts)
constexpr int OFF_RF    = 4096;                 // B*KI   rf (image-token order)
constexpr int OFF_RFF   = OFF_RF + B_SZ * KI;   // B*KF   rf expanded: rf>=0 on-mask, -1 off-mask
// total ≈ 3 MiB

// ---- blocks [0,64): per-(b,feat) mean/(std+eps); blocks [64,320): mask chunk counts
//      (count blocks 0..5 also zero the RAWS/RAWP/RAWN accumulators) ----
__global__ __launch_bounds__(256) void k_stats_cnt(const float* __restrict__ fC,
        const float* __restrict__ fA, const float* __restrict__ fD,
        const float* __restrict__ fB, const int* __restrict__ mask,
        float* __restrict__ ws) {
    __shared__ double r1[256], r2[256];
    __shared__ int sred[256];
    int bid = blockIdx.x, t = threadIdx.x;
    if (bid < 64) {
        int b = bid >> 2, f = bid & 3;
        const float* src;
        if (f == 0) src = fC; else if (f == 1) src = fA; else if (f == 2) src = fD; else src = fB;
        src += (size_t)b * KI;
        double s = 0.0, s2 = 0.0;
        for (int i = t; i < KI / 4; i += 256) {
            float4 v = ((const float4*)src)[i];
            s  += (double)v.x + (double)v.y + (double)v.z + (double)v.w;
            s2 += (double)v.x * v.x + (double)v.y * v.y + (double)v.z * v.z + (double)v.w * v.w;
        }
        r1[t] = s; r2[t] = s2; __syncthreads();
        for (int off = 128; off > 0; off >>= 1) {
            if (t < off) { r1[t] += r1[t + off]; r2[t] += r2[t + off]; }
            __syncthreads();
        }
        if (t == 0) {
            double mu  = r1[0] * (1.0 / KI);
            double var = fmax(r2[0] * (1.0 / KI) - mu * mu, 0.0);
            ws[OFF_MU + bid] = (float)mu;
            ws[OFF_SD + bid] = (float)(sqrt(var) + (double)EPS);
        }
    } else {
        int cblk = bid - 64;                     // 0..255, 2048 ints each
        if (cblk < 6) ws[OFF_RAWS + cblk * 256 + t] = 0.f;   // zero 1536 accum floats
        const int* mrow = mask + (size_t)cblk * 2048;
        int4 m0 = *(const int4*)(mrow + t * 8);
        int4 m1 = *(const int4*)(mrow + t * 8 + 4);
        int cnt = (m0.x != 0) + (m0.y != 0) + (m0.z != 0) + (m0.w != 0)
                + (m1.x != 0) + (m1.y != 0) + (m1.z != 0) + (m1.w != 0);
        sred[t] = cnt; __syncthreads();
        for (int off = 128; off > 0; off >>= 1) {
            if (t < off) sred[t] += sred[t + off];
            __syncthreads();
        }
        if (t == 0) ((int*)ws)[IOFF_BSUM + cblk] = sred[0];
    }
}

// ---- elementwise rf only (low_rf derived by consumers) ----
__global__ __launch_bounds__(256) void k_rf(const float* __restrict__ fC,
        const float* __restrict__ fA, const float* __restrict__ fD,
        const float* __restrict__ fB, float* __restrict__ ws) {
    int blk = blockIdx.x, t = threadIdx.x;       // 256 blocks
    int base = blk * 1024 + t * 4;
    int b = base >> 14;
    const float* mu = ws + OFF_MU + b * 4;
    const float* sd = ws + OFF_SD + b * 4;
    float4 vC = *(const float4*)(fC + base);
    float4 vA = *(const float4*)(fA + base);
    float4 vD = *(const float4*)(fD + base);
    float4 vB = *(const float4*)(fB + base);
    float rf4[4];
    float c4[4] = {vC.x, vC.y, vC.z, vC.w};
    float a4[4] = {vA.x, vA.y, vA.z, vA.w};
    float d4[4] = {vD.x, vD.y, vD.z, vD.w};
    float b4[4] = {vB.x, vB.y, vB.z, vB.w};
    #pragma unroll
    for (int j = 0; j < 4; ++j) {
        float Ct = fmaxf((c4[j] - mu[0]) / sd[0], 0.f);
        float At = 1.f / (1.f + __expf(-((a4[j] - mu[1]) / sd[1])));
        float Dt = 1.f / (1.f + __expf(-((d4[j] - mu[2]) / sd[2])));
        float Bt = 1.f / (1.f + __expf(-((b4[j] - mu[3]) / sd[3])));
        float denom = fmaxf(1.f + 0.5f * (Dt + Bt), EPS);
        rf4[j] = fmaxf(Ct * At / denom, 0.f);
    }
    *(float4*)(ws + OFF_RF + base) = *(float4*)rf4;
}

// ---- expand rf to full-K (rf on-mask, -1 off-mask) via decoupled scan ----
__global__ __launch_bounds__(256) void k_expand(const int* __restrict__ mask,
                                                float* __restrict__ ws) {
    int blk = blockIdx.x, t = threadIdx.x;       // blk = b*16 + c
    int b = blk >> 4, c = blk & 15;
    const int* bsum = (const int*)ws + IOFF_BSUM;
    int boff = 0;
    for (int i = 0; i < c; ++i) boff += bsum[(b << 4) + i];
    const int* mrow = mask + (size_t)blk * 2048;
    int4 m0 = *(const int4*)(mrow + t * 8);
    int4 m1 = *(const int4*)(mrow + t * 8 + 4);
    int mv[8] = {m0.x, m0.y, m0.z, m0.w, m1.x, m1.y, m1.z, m1.w};
    int cnt = 0;
    #pragma unroll
    for (int j = 0; j < 8; ++j) cnt += (mv[j] != 0);
    __shared__ int sc[256];
    sc[t] = cnt; __syncthreads();
    for (int off = 1; off < 256; off <<= 1) {
        int v = (t >= off) ? sc[t - off] : 0;
        __syncthreads();
        sc[t] += v;
        __syncthreads();
    }
    int r = boff + sc[t] - cnt;                  // rank of my first element
    const float* rf = ws + OFF_RF + b * KI;
    float vr[8];
    #pragma unroll
    for (int j = 0; j < 8; ++j) {
        if (mv[j]) { vr[j] = rf[r]; ++r; }
        else       { vr[j] = -1.f; }
    }
    float* rff = ws + OFF_RFF + (size_t)blk * 2048 + t * 8;
    *(float4*)(rff)     = *(float4*)(vr);
    *(float4*)(rff + 4) = *(float4*)(vr + 4);
}

// ---- per-(b,h)-half raw masked-softmax accumulation (branchless, no max-sub: |x|<~6) ----
__global__ __launch_bounds__(256) void k_scores(const float* __restrict__ attn,
                                                float* __restrict__ ws) {
    int g = blockIdx.x, t = threadIdx.x;         // 1024 blocks: bh = g>>1, half = g&1
    int bh = g >> 1, half = g & 1;
    int b = bh >> 5;
    const float* xr  = attn + ((size_t)bh << 15) + ((size_t)half << 14);
    const float* rff = ws + OFF_RFF + ((size_t)b << 15) + ((size_t)half << 14);
    float S = 0.f, P = 0.f, N = 0.f;
    #pragma unroll 4
    for (int i = 0; i < 16; ++i) {
        int k = (i * 256 + t) * 4;
        float4 xs = *(const float4*)(xr + k);
        float4 rv = *(const float4*)(rff + k);
        float xa[4] = {xs.x, xs.y, xs.z, xs.w};
        float va[4] = {rv.x, rv.y, rv.z, rv.w};
        #pragma unroll
        for (int j = 0; j < 4; ++j) {
            float e = __expf(xa[j]);
            bool on = va[j] >= 0.f;
            float rfv  = fmaxf(va[j], 0.f);
            float lrfv = on ? fmaxf(1.f - va[j], 0.f) : 0.f;
            S += on ? e : 0.f;
            P = fmaf(e, rfv, P);
            N = fmaf(e, lrfv, N);
        }
    }
    __shared__ float rs[256], rp[256], rn[256];
    rs[t] = S; rp[t] = P; rn[t] = N;
    __syncthreads();
    for (int off = 128; off > 0; off >>= 1) {
        if (t < off) { rs[t] += rs[t + off]; rp[t] += rp[t + off]; rn[t] += rn[t + off]; }
        __syncthreads();
    }
    if (t == 0) {
        atomicAdd(&ws[OFF_RAWS + bh], rs[0]);
        atomicAdd(&ws[OFF_RAWP + bh], rp[0]);
        atomicAdd(&ws[OFF_RAWN + bh], rn[0]);
    }
}

// ---- out = attn + gp*rf - gn*low_rf; per-block redundant top-k (jax semantics:
//      value desc, tie -> lower index, strictly-positive only) ----
__global__ __launch_bounds__(256) void k_out(const float* __restrict__ attn,
        const float* __restrict__ ws, float* __restrict__ out) {
    unsigned int t = threadIdx.x;
    unsigned int flat = (blockIdx.x * 256 + t) * 4;   // grid covers exactly B*H*KF/4
    unsigned int bh = flat >> 15;                     // uniform per block (1024 | 32768)
    unsigned int b  = bh >> 5;
    unsigned int h  = bh & 31;

    __shared__ float ssp[NH], snv[NH];
    __shared__ int smp[NH];
    __shared__ float s_gp, s_gn;
    if (t < NH) {
        float S0 = ws[OFF_RAWS + b * NH + t];
        ssp[t] = ws[OFF_RAWP + b * NH + t] / S0;
        snv[t] = ws[OFF_RAWN + b * NH + t] / S0;
    }
    __syncthreads();
    if (t < NH) {
        float sp = ssp[t];
        int cnt = 0;
        for (int j = 0; j < NH; ++j) { float o = ssp[j]; cnt += (o > sp) || (o == sp && (int)j < (int)t); }
        smp[t] = (cnt < KHEADS) && (sp > 0.f);
    }
    __syncthreads();
    if (t < NH && smp[t]) snv[t] = -INFINITY;
    __syncthreads();
    if (t == 0) {
        float gp = 0.f, gn = 0.f;
        if (smp[h]) gp = GAMMA;
        else {
            float nv = snv[h];
            int cnt = 0;
            for (int j = 0; j < NH; ++j) { float o = snv[j]; cnt += (o > nv) || (o == nv && j < (int)h); }
            if ((cnt < KHEADS) && (nv > 0.f)) gn = GAMMA;
        }
        s_gp = gp; s_gn = gn;
    }
    __syncthreads();

    float gp = s_gp, gn = s_gn;
    const float* rff = ws + OFF_RFF + ((size_t)b << 15);
    unsigned int k = flat & (KF - 1);
    float4 xs = *(const float4*)(attn + flat);
    float4 rv = *(const float4*)(rff + k);
    float va[4] = {rv.x, rv.y, rv.z, rv.w};
    float xa[4] = {xs.x, xs.y, xs.z, xs.w};
    float oa[4];
    #pragma unroll
    for (int j = 0; j < 4; ++j) {
        bool on = va[j] >= 0.f;
        float rfv  = fmaxf(va[j], 0.f);
        float lrfv = on ? fmaxf(1.f - va[j], 0.f) : 0.f;
        oa[j] = xa[j] + gp * rfv - gn * lrfv;
    }
    float4 o = {oa[0], oa[1], oa[2], oa[3]};
    *(float4*)(out + flat) = o;
}

extern "C" void kernel_launch(void* const* d_in, const int* in_sizes, int n_in,
                              void* d_out, int out_size, void* d_ws, size_t ws_size,
                              hipStream_t stream) {
    const float* attn = (const float*)d_in[0];   // f32 [B,H,KF]
    const int*   mask = (const int*)d_in[1];     // int32 [B,KF]
    const float* fC   = (const float*)d_in[2];   // f32 [B,KI]
    const float* fA   = (const float*)d_in[3];
    const float* fD   = (const float*)d_in[4];
    const float* fB   = (const float*)d_in[5];
    float* out = (float*)d_out;                  // f32 [B,H,KF]
    float* ws = (float*)d_ws;

    k_stats_cnt<<<320, 256, 0, stream>>>(fC, fA, fD, fB, mask, ws);
    k_rf       <<<256, 256, 0, stream>>>(fC, fA, fD, fB, ws);
    k_expand   <<<256, 256, 0, stream>>>(mask, ws);
    k_scores   <<<1024, 256, 0, stream>>>(attn, ws);
    k_out      <<<(B_SZ * NH * KF / 4) / 256, 256, 0, stream>>>(attn, ws, out);
}